// Round 1
// baseline (665.355 us; speedup 1.0000x reference)
//
#include <hip/hip_runtime.h>
#include <hip/hip_bf16.h>

// Problem sizes (fixed by setup_inputs)
#define BATCH 16
#define DMODEL 384
#define LTOK 4096          // H*W = 64*64
#define SDIM 64
#define C3 192             // 3*state_dim
#define DINNER 768

#define BM 64
#define BN 64
#define BK 16

// Generic tiled fp32 GEMM: C[M,N] = A[M,K] * B[K,N] per batch (grid.z).
// bTrans==1 means B is stored as (N x K) row-major (logical B[k][n] = Bp[n*K+k]).
// splitK>1: blockIdx.x encodes (kchunk * nTilesN + ntile); partial results atomicAdd'ed.
__global__ __launch_bounds__(256) void gemm_f32(
    const float* __restrict__ A, const float* __restrict__ Bp, float* __restrict__ C,
    int M, int N, int K,
    long sA, long sB, long sC,
    int nTilesN, int splitK, int bTrans)
{
    const int b = blockIdx.z;
    const float* Ab = A + (long)b * sA;
    const float* Bb = Bp + (long)b * sB;
    float* Cb = C + (long)b * sC;

    const int ntile  = blockIdx.x % nTilesN;
    const int kchunk = blockIdx.x / nTilesN;
    const int mtile  = blockIdx.y;

    const int row0 = mtile * BM;
    const int col0 = ntile * BN;

    const int kPer = K / splitK;
    const int kBeg = kchunk * kPer;
    const int kEnd = kBeg + kPer;

    __shared__ float As[BK][BM + 1];
    __shared__ float Bs[BK][BN + 1];

    const int tx = threadIdx.x;   // 0..15
    const int ty = threadIdx.y;   // 0..15
    const int t  = ty * 16 + tx;  // 0..255

    float acc[4][4];
#pragma unroll
    for (int i = 0; i < 4; i++)
#pragma unroll
        for (int j = 0; j < 4; j++) acc[i][j] = 0.f;

    for (int kt = kBeg; kt < kEnd; kt += BK) {
        // Load A tile (BM x BK), store transposed As[k][m]
#pragma unroll
        for (int r = 0; r < 4; r++) {
            int e = t + r * 256;
            int m = e >> 4, k = e & 15;
            As[k][m] = Ab[(long)(row0 + m) * K + kt + k];
        }
        // Load B tile (BK x BN) -> Bs[k][n]
        if (!bTrans) {
#pragma unroll
            for (int r = 0; r < 4; r++) {
                int e = t + r * 256;
                int k = e >> 6, n = e & 63;
                Bs[k][n] = Bb[(long)(kt + k) * N + col0 + n];
            }
        } else {
#pragma unroll
            for (int r = 0; r < 4; r++) {
                int e = t + r * 256;
                int n = e >> 4, k = e & 15;
                Bs[k][n] = Bb[(long)(col0 + n) * K + kt + k];
            }
        }
        __syncthreads();

#pragma unroll
        for (int kk = 0; kk < BK; kk++) {
            float a[4], bb[4];
#pragma unroll
            for (int i = 0; i < 4; i++) a[i] = As[kk][ty + i * 16];
#pragma unroll
            for (int j = 0; j < 4; j++) bb[j] = Bs[kk][tx + j * 16];
#pragma unroll
            for (int i = 0; i < 4; i++)
#pragma unroll
                for (int j = 0; j < 4; j++) acc[i][j] += a[i] * bb[j];
        }
        __syncthreads();
    }

#pragma unroll
    for (int i = 0; i < 4; i++) {
#pragma unroll
        for (int j = 0; j < 4; j++) {
            long idx = (long)(row0 + ty + i * 16) * N + col0 + tx + j * 16;
            if (splitK > 1) atomicAdd(&Cb[idx], acc[i][j]);
            else            Cb[idx] = acc[i][j];
        }
    }
}

// Depthwise 3x3 conv, padding 1, on 64x64 planes. One block per (b,c) plane.
__global__ __launch_bounds__(256) void dwconv3x3(
    const float* __restrict__ in, const float* __restrict__ w, float* __restrict__ out)
{
    const int bc = blockIdx.x;          // b*C3 + c
    const int c = bc % C3;
    __shared__ float tile[64 * 64];
    __shared__ float wc[9];
    const float* ip = in + (long)bc * 4096;
    for (int i = threadIdx.x; i < 4096; i += 256) tile[i] = ip[i];
    if (threadIdx.x < 9) wc[threadIdx.x] = w[c * 9 + threadIdx.x];
    __syncthreads();
    float* op = out + (long)bc * 4096;
    for (int i = threadIdx.x; i < 4096; i += 256) {
        int y = i >> 6, x = i & 63;
        float s = 0.f;
#pragma unroll
        for (int dy = -1; dy <= 1; dy++) {
#pragma unroll
            for (int dx = -1; dx <= 1; dx++) {
                int yy = y + dy, xx = x + dx;
                if (yy >= 0 && yy < 64 && xx >= 0 && xx < 64)
                    s += tile[yy * 64 + xx] * wc[(dy + 1) * 3 + (dx + 1)];
            }
        }
        op[i] = s;
    }
}

// Per-(b,s) row softmax over L of dt, multiplied by Bm -> AB[b][s][l].
// a_param is constant along L so it cancels in softmax.
__global__ __launch_bounds__(256) void softmax_ab(
    const float* __restrict__ conv, float* __restrict__ AB)
{
    const int b = blockIdx.x >> 6, s = blockIdx.x & 63;
    const float* dt = conv + ((long)b * C3 + 128 + s) * (long)LTOK;
    const float* Bm = conv + ((long)b * C3 + s) * (long)LTOK;
    float* ab = AB + ((long)b * SDIM + s) * (long)LTOK;
    const int t = threadIdx.x;

    float v[16];
    float mx = -1e30f;
#pragma unroll
    for (int i = 0; i < 16; i++) { v[i] = dt[t + i * 256]; mx = fmaxf(mx, v[i]); }
#pragma unroll
    for (int o = 32; o > 0; o >>= 1) mx = fmaxf(mx, __shfl_xor(mx, o));
    __shared__ float redm[4];
    const int wid = t >> 6;
    if ((t & 63) == 0) redm[wid] = mx;
    __syncthreads();
    mx = fmaxf(fmaxf(redm[0], redm[1]), fmaxf(redm[2], redm[3]));

    float sum = 0.f;
#pragma unroll
    for (int i = 0; i < 16; i++) { v[i] = __expf(v[i] - mx); sum += v[i]; }
#pragma unroll
    for (int o = 32; o > 0; o >>= 1) sum += __shfl_xor(sum, o);
    __shared__ float reds[4];
    if ((t & 63) == 0) reds[wid] = sum;
    __syncthreads();
    sum = reds[0] + reds[1] + reds[2] + reds[3];
    const float inv = 1.0f / sum;
#pragma unroll
    for (int i = 0; i < 16; i++)
        ab[t + i * 256] = v[i] * inv * Bm[t + i * 256];
}

// g = h_i * (silu(z) + d), elementwise over (B, DINNER, SDIM)
__global__ __launch_bounds__(256) void gate_k(
    const float* __restrict__ hz, const float* __restrict__ d_param, float* __restrict__ g)
{
    const long i = (long)blockIdx.x * 256 + threadIdx.x;
    const long per = (long)DINNER * SDIM;           // 49152
    const long b = i / per, r = i % per;
    const float hi = hz[b * (2L * per) + r];
    const float z  = hz[b * (2L * per) + per + r];
    const float sil = z / (1.f + __expf(-z));
    g[i] = hi * (sil + d_param[0]);
}

extern "C" void kernel_launch(void* const* d_in, const int* in_sizes, int n_in,
                              void* d_out, int out_size, void* d_ws, size_t ws_size,
                              hipStream_t stream) {
    const float* x      = (const float*)d_in[0];   // (16,384,4096)
    const float* w_bcdt = (const float*)d_in[1];   // (192,384)
    const float* w_dw   = (const float*)d_in[2];   // (192,1,3,3)
    const float* w_hz   = (const float*)d_in[3];   // (1536,384)
    const float* w_out  = (const float*)d_in[4];   // (384,768)
    const float* dparam = (const float*)d_in[6];   // (1,)

    float* ws   = (float*)d_ws;
    float* bcdt = ws;                         // (16,192,4096)  50.3 MB
    float* conv = ws + 12582912;              // (16,192,4096)  50.3 MB
    // after conv, raw bcdt region is reused:
    float* AB   = ws;                         // (16,64,4096)
    float* h    = ws + 4194304;               // (16,384,64)
    float* hz   = ws + 4587520;               // (16,1536,64)
    float* g    = ws + 6160384;               // (16,768,64)

    float* y    = (float*)d_out;              // (16,384,4096)
    float* hout = (float*)d_out + 25165824;   // (16,384,64)

    dim3 blk(16, 16);

    // 1) bc_dt = w_bcdt @ x_b   (M=192, N=4096, K=384)
    gemm_f32<<<dim3(64, 3, BATCH), blk, 0, stream>>>(
        w_bcdt, x, bcdt, C3, LTOK, DMODEL,
        0L, (long)DMODEL * LTOK, (long)C3 * LTOK, 64, 1, 0);

    // 2) depthwise 3x3 conv
    dwconv3x3<<<dim3(BATCH * C3), 256, 0, stream>>>(bcdt, w_dw, conv);

    // 3) softmax(dt) * Bm -> AB (stored (b, s, l))
    softmax_ab<<<dim3(BATCH * SDIM), 256, 0, stream>>>(conv, AB);

    // 4) h[b,d,s] = sum_l x[b,d,l] * AB[b,s,l]   (M=384,N=64,K=4096, split-K=8)
    hipMemsetAsync(h, 0, (size_t)BATCH * DMODEL * SDIM * sizeof(float), stream);
    gemm_f32<<<dim3(8, 6, BATCH), blk, 0, stream>>>(
        x, AB, h, DMODEL, SDIM, LTOK,
        (long)DMODEL * LTOK, (long)SDIM * LTOK, (long)DMODEL * SDIM, 1, 8, 1);

    // 5) hz = w_hz @ h_b   (M=1536, N=64, K=384)
    gemm_f32<<<dim3(1, 24, BATCH), blk, 0, stream>>>(
        w_hz, h, hz, 2 * DINNER, SDIM, DMODEL,
        0L, (long)DMODEL * SDIM, (long)2 * DINNER * SDIM, 1, 1, 0);

    // 6) gate
    gate_k<<<dim3((BATCH * DINNER * SDIM) / 256), 256, 0, stream>>>(hz, dparam, g);

    // 7) hout = w_out @ g_b   (M=384, N=64, K=768) -> second output region
    gemm_f32<<<dim3(1, 6, BATCH), blk, 0, stream>>>(
        w_out, g, hout, DMODEL, SDIM, DINNER,
        0L, (long)DINNER * SDIM, (long)DMODEL * SDIM, 1, 1, 0);

    // 8) y = hout_b @ Cm_b   (M=384, N=4096, K=64), Cm = conv channels 64..127
    gemm_f32<<<dim3(64, 6, BATCH), blk, 0, stream>>>(
        hout, conv + (long)SDIM * LTOK, y, DMODEL, LTOK, SDIM,
        (long)DMODEL * SDIM, (long)C3 * LTOK, (long)DMODEL * LTOK, 64, 1, 0);
}

// Round 2
// 356.299 us; speedup vs baseline: 1.8674x; 1.8674x over previous
//
#include <hip/hip_runtime.h>
#include <hip/hip_bf16.h>

#define BATCH 16
#define DMODEL 384
#define LTOK 4096          // H*W
#define SDIM 64
#define C3 192
#define DINNER 768

typedef __attribute__((ext_vector_type(8))) short short8;
typedef __attribute__((ext_vector_type(4))) float f32x4;

__device__ __forceinline__ short f2bf(float f) {
    unsigned u = __builtin_bit_cast(unsigned, f);
    u += 0x7fffu + ((u >> 16) & 1u);   // round-to-nearest-even
    return (short)(u >> 16);
}

// ---------------------------------------------------------------------------
// Unified MFMA bf16 GEMM:  C(M x N, fp32) = A(M x K) * B(K x N)
// where B is provided TRANSPOSED: Bp is (N x K) row-major.
// AF32/BF32: operand stored fp32 in global, converted to bf16 during staging.
// ATOMIC: split-K partials accumulated with atomicAdd (C must be pre-zeroed).
// Geometry: BM=64 fixed, BK=32, 4 waves; wave w owns cols [w*BN/4, (w+1)*BN/4).
// Fragments per wave: 4 (M) x NF (N), NF = BN/64.
// ---------------------------------------------------------------------------
template<int BN, int NF, bool AF32, bool BF32, bool ATOMIC>
__global__ __launch_bounds__(256) void gemm_bf16(
    const void* __restrict__ Ap, const void* __restrict__ Bp, float* __restrict__ Cp,
    int M, int N, int K, long sA, long sB, long sC, int nTilesN, int splitK)
{
    const int b = blockIdx.z;
    const int ntile  = blockIdx.x % nTilesN;
    const int kchunk = blockIdx.x / nTilesN;
    const int row0 = blockIdx.y << 6;
    const int col0 = ntile * BN;
    const int kPer = K / splitK;
    const int kBeg = kchunk * kPer, kEnd = kBeg + kPer;

    __shared__ short As[64][40];     // 8-bf16 pad -> ~2-way bank conflicts (free)
    __shared__ short Bs[BN][40];

    const int t = threadIdx.x;
    const int wid = t >> 6, lane = t & 63;
    const int lr = lane & 15;
    const int lk = (lane >> 4) << 3;

    f32x4 acc[4][NF];
#pragma unroll
    for (int i = 0; i < 4; i++)
#pragma unroll
        for (int j = 0; j < NF; j++)
#pragma unroll
            for (int r = 0; r < 4; r++) acc[i][j][r] = 0.f;

    for (int kt = kBeg; kt < kEnd; kt += 32) {
        // ---- stage A tile (64 x 32) ----
        {
            const int arow = t >> 2, akb = (t & 3) << 3;
            if constexpr (AF32) {
                const float* s = (const float*)Ap + b * sA + (long)(row0 + arow) * K + kt + akb;
                short8 v;
#pragma unroll
                for (int j = 0; j < 8; j++) v[j] = f2bf(s[j]);
                *(short8*)&As[arow][akb] = v;
            } else {
                const short* s = (const short*)Ap + b * sA + (long)(row0 + arow) * K + kt + akb;
                *(short8*)&As[arow][akb] = *(const short8*)s;
            }
        }
        // ---- stage B tile (BN x 32) from (N x K)-stored operand ----
#pragma unroll
        for (int rr = 0; rr < BN / 64; rr++) {
            const int u = t + rr * 256;
            const int brow = u >> 2, bkb = (u & 3) << 3;
            if constexpr (BF32) {
                const float* s = (const float*)Bp + b * sB + (long)(col0 + brow) * K + kt + bkb;
                short8 v;
#pragma unroll
                for (int j = 0; j < 8; j++) v[j] = f2bf(s[j]);
                *(short8*)&Bs[brow][bkb] = v;
            } else {
                const short* s = (const short*)Bp + b * sB + (long)(col0 + brow) * K + kt + bkb;
                *(short8*)&Bs[brow][bkb] = *(const short8*)s;
            }
        }
        __syncthreads();

        short8 af[4], bfr[NF];
#pragma unroll
        for (int mi = 0; mi < 4; mi++) af[mi] = *(const short8*)&As[mi * 16 + lr][lk];
#pragma unroll
        for (int ni = 0; ni < NF; ni++) bfr[ni] = *(const short8*)&Bs[wid * (BN / 4) + ni * 16 + lr][lk];
#pragma unroll
        for (int mi = 0; mi < 4; mi++)
#pragma unroll
            for (int ni = 0; ni < NF; ni++)
                acc[mi][ni] = __builtin_amdgcn_mfma_f32_16x16x32_bf16(af[mi], bfr[ni], acc[mi][ni], 0, 0, 0);
        __syncthreads();
    }

    float* Cb = Cp + b * sC;
#pragma unroll
    for (int mi = 0; mi < 4; mi++)
#pragma unroll
        for (int ni = 0; ni < NF; ni++)
#pragma unroll
            for (int r = 0; r < 4; r++) {
                const long row = row0 + mi * 16 + ((lane >> 4) << 2) + r;
                const long col = col0 + wid * (BN / 4) + ni * 16 + lr;
                if constexpr (ATOMIC) atomicAdd(&Cb[row * N + col], acc[mi][ni][r]);
                else                  Cb[row * N + col] = acc[mi][ni][r];
            }
}

// x (b,384,4096 f32) -> xbT (b,4096,384 bf16), 64x64 LDS tiles
__global__ __launch_bounds__(256) void transpose_x(const float* __restrict__ x, short* __restrict__ xbT)
{
    const int b = blockIdx.z;
    const int l0 = blockIdx.x << 6, d0 = blockIdx.y << 6;
    __shared__ float tl[64][65];
    const int t = threadIdx.x, c = t & 63, r0 = t >> 6;
    const float* ip = x + ((long)b * DMODEL + d0) * LTOK + l0;
    for (int d = r0; d < 64; d += 4) tl[d][c] = ip[(long)d * LTOK + c];
    __syncthreads();
    short* op = xbT + ((long)b * LTOK + l0) * DMODEL + d0;
    for (int l = r0; l < 64; l += 4) op[(long)l * DMODEL + c] = f2bf(tl[c][l]);
}

// Depthwise 3x3 conv, padding 1, on 64x64 planes. One block per (b,c) plane.
__global__ __launch_bounds__(256) void dwconv3x3(
    const float* __restrict__ in, const float* __restrict__ w, float* __restrict__ out)
{
    const int bc = blockIdx.x;
    const int c = bc % C3;
    __shared__ float tile[64 * 64];
    __shared__ float wc[9];
    const float* ip = in + (long)bc * 4096;
    for (int i = threadIdx.x; i < 4096; i += 256) tile[i] = ip[i];
    if (threadIdx.x < 9) wc[threadIdx.x] = w[c * 9 + threadIdx.x];
    __syncthreads();
    float* op = out + (long)bc * 4096;
    for (int i = threadIdx.x; i < 4096; i += 256) {
        int y = i >> 6, x = i & 63;
        float s = 0.f;
#pragma unroll
        for (int dy = -1; dy <= 1; dy++)
#pragma unroll
            for (int dx = -1; dx <= 1; dx++) {
                int yy = y + dy, xx = x + dx;
                if (yy >= 0 && yy < 64 && xx >= 0 && xx < 64)
                    s += tile[yy * 64 + xx] * wc[(dy + 1) * 3 + (dx + 1)];
            }
        op[i] = s;
    }
}

// softmax over L of dt (a_param cancels), * Bm -> AB bf16 (b, s, l)
__global__ __launch_bounds__(256) void softmax_ab(
    const float* __restrict__ conv, short* __restrict__ AB)
{
    const int b = blockIdx.x >> 6, s = blockIdx.x & 63;
    const float* dt = conv + ((long)b * C3 + 128 + s) * (long)LTOK;
    const float* Bm = conv + ((long)b * C3 + s) * (long)LTOK;
    short* ab = AB + ((long)b * SDIM + s) * (long)LTOK;
    const int t = threadIdx.x;

    float v[16];
    float mx = -1e30f;
#pragma unroll
    for (int i = 0; i < 16; i++) { v[i] = dt[t + i * 256]; mx = fmaxf(mx, v[i]); }
#pragma unroll
    for (int o = 32; o > 0; o >>= 1) mx = fmaxf(mx, __shfl_xor(mx, o));
    __shared__ float redm[4];
    const int wid = t >> 6;
    if ((t & 63) == 0) redm[wid] = mx;
    __syncthreads();
    mx = fmaxf(fmaxf(redm[0], redm[1]), fmaxf(redm[2], redm[3]));

    float sum = 0.f;
#pragma unroll
    for (int i = 0; i < 16; i++) { v[i] = __expf(v[i] - mx); sum += v[i]; }
#pragma unroll
    for (int o = 32; o > 0; o >>= 1) sum += __shfl_xor(sum, o);
    __shared__ float reds[4];
    if ((t & 63) == 0) reds[wid] = sum;
    __syncthreads();
    sum = reds[0] + reds[1] + reds[2] + reds[3];
    const float inv = 1.0f / sum;
#pragma unroll
    for (int i = 0; i < 16; i++)
        ab[t + i * 256] = f2bf(v[i] * inv * Bm[t + i * 256]);
}

// gT[b,s,o] = hzT[b,s,o] * (silu(hzT[b,s,768+o]) + d)
__global__ __launch_bounds__(256) void gate_k(
    const float* __restrict__ hzT, const float* __restrict__ d_param, float* __restrict__ gT)
{
    const long i = (long)blockIdx.x * 256 + threadIdx.x;   // over 16*64*768
    const long b = i / (SDIM * DINNER), r = i % (SDIM * DINNER);
    const long s = r / DINNER, o = r % DINNER;
    const float* hp = hzT + b * (SDIM * 2L * DINNER) + s * (2L * DINNER);
    const float hi = hp[o];
    const float z  = hp[DINNER + o];
    const float sil = z / (1.f + __expf(-z));
    gT[i] = hi * (sil + d_param[0]);
}

// houtT (b,64,384 f32) -> hout (b,384,64 f32, output) + hb (bf16)
__global__ __launch_bounds__(256) void transpose_hout(
    const float* __restrict__ houtT, float* __restrict__ hout, short* __restrict__ hb)
{
    const int b = blockIdx.y, d0 = blockIdx.x << 6;
    __shared__ float tl[64][65];
    const int t = threadIdx.x, c = t & 63, r0 = t >> 6;
    const float* ip = houtT + (long)b * SDIM * DMODEL + d0;       // [s][d]
    for (int s = r0; s < 64; s += 4) tl[s][c] = ip[(long)s * DMODEL + c];
    __syncthreads();
    float* op = hout + ((long)b * DMODEL + d0) * SDIM;
    short* ob = hb + ((long)b * DMODEL + d0) * SDIM;
    for (int d = r0; d < 64; d += 4) {
        float v = tl[c][d];                                        // out[d][s=c]
        op[(long)d * SDIM + c] = v;
        ob[(long)d * SDIM + c] = f2bf(v);
    }
}

// conv channels 64..127 (b,s,l f32) -> CmT (b,l,s bf16)
__global__ __launch_bounds__(256) void transpose_cm(
    const float* __restrict__ conv, short* __restrict__ CmT)
{
    const int b = blockIdx.y, l0 = blockIdx.x << 6;
    __shared__ float tl[64][65];
    const int t = threadIdx.x, c = t & 63, r0 = t >> 6;
    const float* ip = conv + ((long)b * C3 + SDIM) * LTOK + l0;    // [s][l]
    for (int s = r0; s < 64; s += 4) tl[s][c] = ip[(long)s * LTOK + c];
    __syncthreads();
    short* op = CmT + ((long)b * LTOK + l0) * SDIM;
    for (int l = r0; l < 64; l += 4) op[(long)l * SDIM + c] = f2bf(tl[c][l]);
}

extern "C" void kernel_launch(void* const* d_in, const int* in_sizes, int n_in,
                              void* d_out, int out_size, void* d_ws, size_t ws_size,
                              hipStream_t stream) {
    const float* x      = (const float*)d_in[0];   // (16,384,4096)
    const float* w_bcdt = (const float*)d_in[1];   // (192,384)
    const float* w_dw   = (const float*)d_in[2];   // (192,1,3,3)
    const float* w_hz   = (const float*)d_in[3];   // (1536,384)
    const float* w_out  = (const float*)d_in[4];   // (384,768)
    const float* dparam = (const float*)d_in[6];   // (1,)

    char* ws = (char*)d_ws;
    // region A (50.33 MB): xbT during gemm1, then conv
    short* xbT  = (short*)ws;
    float* conv = (float*)ws;
    // region B (50.33 MB): bcdt during gemm1+dwconv, then small tensors
    float* bcdt  = (float*)(ws + 50331648);
    short* AB    = (short*)(ws + 50331648);   //  8.39 MB (b,64,4096) bf16
    short* CmT   = (short*)(ws + 58720256);   //  8.39 MB (b,4096,64) bf16
    float* hT    = (float*)(ws + 67108864);   //  1.57 MB (b,64,384)
    float* hzT   = (float*)(ws + 68681728);   //  6.29 MB (b,64,1536)
    float* gT    = (float*)(ws + 74973184);   //  3.15 MB (b,64,768)
    float* houtT = (float*)(ws + 78118912);   //  1.57 MB (b,64,384)
    short* hb    = (short*)(ws + 79691776);   //  0.79 MB (b,384,64) bf16

    float* y    = (float*)d_out;               // (16,384,4096)
    float* hout = (float*)d_out + 25165824;    // (16,384,64)

    // 1) x -> xbT (transposed bf16)
    transpose_x<<<dim3(64, 6, 16), 256, 0, stream>>>(x, xbT);

    // 2) bcdt[b] = w_bcdt @ x[b]   (M=192, N=4096, K=384); B from xbT
    gemm_bf16<128, 2, true, false, false><<<dim3(32, 3, BATCH), 256, 0, stream>>>(
        w_bcdt, xbT, bcdt, C3, LTOK, DMODEL,
        0L, (long)LTOK * DMODEL, (long)C3 * LTOK, 32, 1);

    // 3) depthwise conv (fp32)
    dwconv3x3<<<dim3(BATCH * C3), 256, 0, stream>>>(bcdt, w_dw, conv);

    // 4) AB bf16 = softmax(dt) * Bm
    softmax_ab<<<dim3(BATCH * SDIM), 256, 0, stream>>>(conv, AB);

    // 5) hT[b] (64x384) = AB[b] (64x4096) @ x[b]^T ; split-K=8, atomics
    hipMemsetAsync(hT, 0, (size_t)BATCH * SDIM * DMODEL * 4, stream);
    gemm_bf16<128, 2, false, true, true><<<dim3(3 * 8, 1, BATCH), 256, 0, stream>>>(
        AB, x, hT, SDIM, DMODEL, LTOK,
        (long)SDIM * LTOK, (long)DMODEL * LTOK, (long)SDIM * DMODEL, 3, 8);

    // 6) hzT[b] (64x1536) = hT[b] @ w_hz^T   (K=384)
    gemm_bf16<128, 2, true, true, false><<<dim3(12, 1, BATCH), 256, 0, stream>>>(
        hT, w_hz, hzT, SDIM, 2 * DINNER, DMODEL,
        (long)SDIM * DMODEL, 0L, (long)SDIM * 2 * DINNER, 12, 1);

    // 7) gate: gT = h_i * (silu(z) + d)
    gate_k<<<dim3((BATCH * SDIM * DINNER) / 256), 256, 0, stream>>>(hzT, dparam, gT);

    // 8) houtT[b] (64x384) = gT[b] (64x768) @ w_out^T
    gemm_bf16<128, 2, true, true, false><<<dim3(3, 1, BATCH), 256, 0, stream>>>(
        gT, w_out, houtT, SDIM, DMODEL, DINNER,
        (long)SDIM * DINNER, 0L, (long)SDIM * DMODEL, 3, 1);

    // 9) houtT -> hout (output 2) + hb bf16
    transpose_hout<<<dim3(6, 16), 256, 0, stream>>>(houtT, hout, hb);

    // 10) Cm -> CmT bf16
    transpose_cm<<<dim3(64, 16), 256, 0, stream>>>(conv, CmT);

    // 11) y[b] (384x4096) = hb[b] (384x64) @ CmT[b]^T (K=64)
    gemm_bf16<128, 2, false, false, false><<<dim3(32, 6, BATCH), 256, 0, stream>>>(
        hb, CmT, y, DMODEL, LTOK, SDIM,
        (long)DMODEL * SDIM, (long)LTOK * SDIM, (long)DMODEL * LTOK, 32, 1);
}

// Round 4
// 352.996 us; speedup vs baseline: 1.8849x; 1.0094x over previous
//
#include <hip/hip_runtime.h>
#include <hip/hip_bf16.h>

#define BATCH 16
#define DMODEL 384
#define LTOK 4096          // H*W
#define SDIM 64
#define C3 192
#define DINNER 768

typedef __attribute__((ext_vector_type(8))) short short8;
typedef __attribute__((ext_vector_type(4))) float f32x4;

__device__ __forceinline__ short f2bf(float f) {
    unsigned u = __builtin_bit_cast(unsigned, f);
    u += 0x7fffu + ((u >> 16) & 1u);   // round-to-nearest-even
    return (short)(u >> 16);
}
__device__ __forceinline__ float bf2f(short s) {
    return __builtin_bit_cast(float, ((unsigned)(unsigned short)s) << 16);
}

// ---------------------------------------------------------------------------
// Unified MFMA bf16 GEMM:  C(M x N) = A(M x K) * B(K x N)
// B provided TRANSPOSED: Bp is (N x K) row-major.
// AF32/BF32: operand stored fp32 in global, converted to bf16 during staging.
// CMODE: 0 = fp32 store, 1 = fp32 atomicAdd (split-K), 2 = bf16 store.
// Geometry: BM=64, BK=32, 4 waves; wave w owns cols [w*BN/4, (w+1)*BN/4).
// ---------------------------------------------------------------------------
template<int BN, int NF, bool AF32, bool BF32, int CMODE>
__global__ __launch_bounds__(256) void gemm_bf16(
    const void* __restrict__ Ap, const void* __restrict__ Bp, void* __restrict__ Cp,
    int M, int N, int K, long sA, long sB, long sC, int nTilesN, int splitK)
{
    const int b = blockIdx.z;
    const int ntile  = blockIdx.x % nTilesN;
    const int kchunk = blockIdx.x / nTilesN;
    const int row0 = blockIdx.y << 6;
    const int col0 = ntile * BN;
    const int kPer = K / splitK;
    const int kBeg = kchunk * kPer, kEnd = kBeg + kPer;

    __shared__ short As[64][40];
    __shared__ short Bs[BN][40];

    const int t = threadIdx.x;
    const int wid = t >> 6, lane = t & 63;
    const int lr = lane & 15;
    const int lk = (lane >> 4) << 3;

    f32x4 acc[4][NF];
#pragma unroll
    for (int i = 0; i < 4; i++)
#pragma unroll
        for (int j = 0; j < NF; j++)
#pragma unroll
            for (int r = 0; r < 4; r++) acc[i][j][r] = 0.f;

    for (int kt = kBeg; kt < kEnd; kt += 32) {
        // ---- stage A tile (64 x 32) ----
        {
            const int arow = t >> 2, akb = (t & 3) << 3;
            if constexpr (AF32) {
                const float* s = (const float*)Ap + b * sA + (long)(row0 + arow) * K + kt + akb;
                short8 v;
#pragma unroll
                for (int j = 0; j < 8; j++) v[j] = f2bf(s[j]);
                *(short8*)&As[arow][akb] = v;
            } else {
                const short* s = (const short*)Ap + b * sA + (long)(row0 + arow) * K + kt + akb;
                *(short8*)&As[arow][akb] = *(const short8*)s;
            }
        }
        // ---- stage B tile (BN x 32) from (N x K)-stored operand ----
#pragma unroll
        for (int rr = 0; rr < BN / 64; rr++) {
            const int u = t + rr * 256;
            const int brow = u >> 2, bkb = (u & 3) << 3;
            if constexpr (BF32) {
                const float* s = (const float*)Bp + b * sB + (long)(col0 + brow) * K + kt + bkb;
                short8 v;
#pragma unroll
                for (int j = 0; j < 8; j++) v[j] = f2bf(s[j]);
                *(short8*)&Bs[brow][bkb] = v;
            } else {
                const short* s = (const short*)Bp + b * sB + (long)(col0 + brow) * K + kt + bkb;
                *(short8*)&Bs[brow][bkb] = *(const short8*)s;
            }
        }
        __syncthreads();

        short8 af[4], bfr[NF];
#pragma unroll
        for (int mi = 0; mi < 4; mi++) af[mi] = *(const short8*)&As[mi * 16 + lr][lk];
#pragma unroll
        for (int ni = 0; ni < NF; ni++) bfr[ni] = *(const short8*)&Bs[wid * (BN / 4) + ni * 16 + lr][lk];
#pragma unroll
        for (int mi = 0; mi < 4; mi++)
#pragma unroll
            for (int ni = 0; ni < NF; ni++)
                acc[mi][ni] = __builtin_amdgcn_mfma_f32_16x16x32_bf16(af[mi], bfr[ni], acc[mi][ni], 0, 0, 0);
        __syncthreads();
    }

#pragma unroll
    for (int mi = 0; mi < 4; mi++)
#pragma unroll
        for (int ni = 0; ni < NF; ni++)
#pragma unroll
            for (int r = 0; r < 4; r++) {
                const long row = row0 + mi * 16 + ((lane >> 4) << 2) + r;
                const long col = col0 + wid * (BN / 4) + ni * 16 + lr;
                if constexpr (CMODE == 1)      atomicAdd((float*)Cp + b * sC + row * N + col, acc[mi][ni][r]);
                else if constexpr (CMODE == 2) *((short*)Cp + b * sC + row * N + col) = f2bf(acc[mi][ni][r]);
                else                           *((float*)Cp + b * sC + row * N + col) = acc[mi][ni][r];
            }
}

// x (b,384,4096 f32) -> xbT (b,4096,384 bf16), 64x64 LDS tiles
__global__ __launch_bounds__(256) void transpose_x(const float* __restrict__ x, short* __restrict__ xbT)
{
    const int b = blockIdx.z;
    const int l0 = blockIdx.x << 6, d0 = blockIdx.y << 6;
    __shared__ float tl[64][65];
    const int t = threadIdx.x, c = t & 63, r0 = t >> 6;
    const float* ip = x + ((long)b * DMODEL + d0) * LTOK + l0;
    for (int d = r0; d < 64; d += 4) tl[d][c] = ip[(long)d * LTOK + c];
    __syncthreads();
    short* op = xbT + ((long)b * LTOK + l0) * DMODEL + d0;
    for (int l = r0; l < 64; l += 4) op[(long)l * DMODEL + c] = f2bf(tl[c][l]);
}

// Fused: depthwise 3x3 conv of Bm(ch s) and dt(ch 128+s) + softmax(dt) * Bm -> AB bf16
// One block per (b, s). bcdt is bf16 (b, 192, 4096).
__global__ __launch_bounds__(256) void conv_softmax_ab(
    const short* __restrict__ bcdt, const float* __restrict__ w_dw, short* __restrict__ AB)
{
    const int b = blockIdx.x >> 6, s = blockIdx.x & 63;
    __shared__ float pB[4096];
    __shared__ float pD[4096];
    __shared__ float wB[9], wD[9];
    __shared__ float redm[4], reds[4];
    const int t = threadIdx.x;

    const short* srcB = bcdt + ((long)b * C3 + s) * 4096;
    const short* srcD = bcdt + ((long)b * C3 + 128 + s) * 4096;
#pragma unroll
    for (int j = 0; j < 2; j++) {
        const int o = (t + j * 256) * 8;
        short8 vb = *(const short8*)(srcB + o);
        short8 vd = *(const short8*)(srcD + o);
#pragma unroll
        for (int e = 0; e < 8; e++) { pB[o + e] = bf2f(vb[e]); pD[o + e] = bf2f(vd[e]); }
    }
    if (t < 9) { wB[t] = w_dw[s * 9 + t]; wD[t] = w_dw[(128 + s) * 9 + t]; }
    __syncthreads();

    // conv(dt) at l = t + i*256
    float v[16];
    float mx = -1e30f;
#pragma unroll
    for (int i = 0; i < 16; i++) {
        const int l = t + i * 256, y = l >> 6, x = l & 63;
        float sacc = 0.f;
#pragma unroll
        for (int dy = -1; dy <= 1; dy++)
#pragma unroll
            for (int dx = -1; dx <= 1; dx++) {
                int yy = y + dy, xx = x + dx;
                if (yy >= 0 && yy < 64 && xx >= 0 && xx < 64)
                    sacc += pD[yy * 64 + xx] * wD[(dy + 1) * 3 + (dx + 1)];
            }
        v[i] = sacc; mx = fmaxf(mx, sacc);
    }
#pragma unroll
    for (int o = 32; o > 0; o >>= 1) mx = fmaxf(mx, __shfl_xor(mx, o));
    const int wid = t >> 6;
    if ((t & 63) == 0) redm[wid] = mx;
    __syncthreads();
    mx = fmaxf(fmaxf(redm[0], redm[1]), fmaxf(redm[2], redm[3]));

    float sum = 0.f;
#pragma unroll
    for (int i = 0; i < 16; i++) { v[i] = __expf(v[i] - mx); sum += v[i]; }
#pragma unroll
    for (int o = 32; o > 0; o >>= 1) sum += __shfl_xor(sum, o);
    if ((t & 63) == 0) reds[wid] = sum;
    __syncthreads();
    sum = reds[0] + reds[1] + reds[2] + reds[3];
    const float inv = 1.0f / sum;

    short* ab = AB + ((long)b * SDIM + s) * (long)LTOK;
#pragma unroll
    for (int i = 0; i < 16; i++) {
        const int l = t + i * 256, y = l >> 6, x = l & 63;
        float uacc = 0.f;
#pragma unroll
        for (int dy = -1; dy <= 1; dy++)
#pragma unroll
            for (int dx = -1; dx <= 1; dx++) {
                int yy = y + dy, xx = x + dx;
                if (yy >= 0 && yy < 64 && xx >= 0 && xx < 64)
                    uacc += pB[yy * 64 + xx] * wB[(dy + 1) * 3 + (dx + 1)];
            }
        ab[l] = f2bf(v[i] * inv * uacc);
    }
}

// Depthwise conv for Cm channels only (c = 64+cc), bcdt bf16 in, fp32 out (b,64,4096)
__global__ __launch_bounds__(256) void dwconv_cm(
    const short* __restrict__ bcdt, const float* __restrict__ w, float* __restrict__ convCm)
{
    const int bc = blockIdx.x;            // b*64 + cc
    const int b = bc >> 6, cc = bc & 63;
    __shared__ float tile[4096];
    __shared__ float wc[9];
    const short* ip = bcdt + ((long)b * C3 + 64 + cc) * 4096;
    const int t = threadIdx.x;
#pragma unroll
    for (int j = 0; j < 2; j++) {
        const int o = (t + j * 256) * 8;
        short8 vv = *(const short8*)(ip + o);
#pragma unroll
        for (int e = 0; e < 8; e++) tile[o + e] = bf2f(vv[e]);
    }
    if (t < 9) wc[t] = w[(64 + cc) * 9 + t];
    __syncthreads();
    float* op = convCm + (long)bc * 4096;
    for (int i = t; i < 4096; i += 256) {
        int y = i >> 6, x = i & 63;
        float sacc = 0.f;
#pragma unroll
        for (int dy = -1; dy <= 1; dy++)
#pragma unroll
            for (int dx = -1; dx <= 1; dx++) {
                int yy = y + dy, xx = x + dx;
                if (yy >= 0 && yy < 64 && xx >= 0 && xx < 64)
                    sacc += tile[yy * 64 + xx] * wc[(dy + 1) * 3 + (dx + 1)];
            }
        op[i] = sacc;
    }
}

// convCm (b,64,4096 f32) -> CmT (b,4096,64 bf16)
__global__ __launch_bounds__(256) void transpose_cm(
    const float* __restrict__ convCm, short* __restrict__ CmT)
{
    const int b = blockIdx.y, l0 = blockIdx.x << 6;
    __shared__ float tl[64][65];
    const int t = threadIdx.x, c = t & 63, r0 = t >> 6;
    const float* ip = convCm + (long)b * SDIM * LTOK + l0;   // [s][l]
    for (int s = r0; s < 64; s += 4) tl[s][c] = ip[(long)s * LTOK + c];
    __syncthreads();
    short* op = CmT + ((long)b * LTOK + l0) * SDIM;
    for (int l = r0; l < 64; l += 4) op[(long)l * SDIM + c] = f2bf(tl[c][l]);
}

// gT[b,s,o] = hzT[b,s,o] * (silu(hzT[b,s,768+o]) + d)
__global__ __launch_bounds__(256) void gate_k(
    const float* __restrict__ hzT, const float* __restrict__ d_param, float* __restrict__ gT)
{
    const long i = (long)blockIdx.x * 256 + threadIdx.x;
    const long b = i / (SDIM * DINNER), r = i % (SDIM * DINNER);
    const long s = r / DINNER, o = r % DINNER;
    const float* hp = hzT + b * (SDIM * 2L * DINNER) + s * (2L * DINNER);
    const float hi = hp[o];
    const float z  = hp[DINNER + o];
    const float sil = z / (1.f + __expf(-z));
    gT[i] = hi * (sil + d_param[0]);
}

// houtT (b,64,384 f32) -> hout (b,384,64 f32, output 2) + hb (bf16)
__global__ __launch_bounds__(256) void transpose_hout(
    const float* __restrict__ houtT, float* __restrict__ hout, short* __restrict__ hb)
{
    const int b = blockIdx.y, d0 = blockIdx.x << 6;
    __shared__ float tl[64][65];
    const int t = threadIdx.x, c = t & 63, r0 = t >> 6;
    const float* ip = houtT + (long)b * SDIM * DMODEL + d0;
    for (int s = r0; s < 64; s += 4) tl[s][c] = ip[(long)s * DMODEL + c];
    __syncthreads();
    float* op = hout + ((long)b * DMODEL + d0) * SDIM;
    short* ob = hb + ((long)b * DMODEL + d0) * SDIM;
    for (int d = r0; d < 64; d += 4) {
        float v = tl[c][d];
        op[(long)d * SDIM + c] = v;
        ob[(long)d * SDIM + c] = f2bf(v);
    }
}

extern "C" void kernel_launch(void* const* d_in, const int* in_sizes, int n_in,
                              void* d_out, int out_size, void* d_ws, size_t ws_size,
                              hipStream_t stream) {
    const float* x      = (const float*)d_in[0];   // (16,384,4096)
    const float* w_bcdt = (const float*)d_in[1];   // (192,384)
    const float* w_dw   = (const float*)d_in[2];   // (192,1,3,3)
    const float* w_hz   = (const float*)d_in[3];   // (1536,384)
    const float* w_out  = (const float*)d_in[4];   // (384,768)
    const float* dparam = (const float*)d_in[6];   // (1,)

    char* ws = (char*)d_ws;
    short* xbT    = (short*)(ws);                  // 50.33 MB (b,4096,384) bf16
    short* bcdt   = (short*)(ws + 50331648);       // 25.17 MB (b,192,4096) bf16
    short* AB     = (short*)(ws + 75497472);       //  8.39 MB (b,64,4096)  bf16
    float* convCm = (float*)(ws + 83886080);       // 16.78 MB (b,64,4096)  f32
    short* CmT    = (short*)(ws + 100663296);      //  8.39 MB (b,4096,64)  bf16
    float* hT     = (float*)(ws + 109051904);      //  1.57 MB (b,64,384)
    float* hzT    = (float*)(ws + 110624768);      //  6.29 MB (b,64,1536)
    float* gT     = (float*)(ws + 116916224);      //  3.15 MB (b,64,768)
    float* houtT  = (float*)(ws + 120061952);      //  1.57 MB (b,64,384)
    short* hb     = (short*)(ws + 121634816);      //  0.79 MB (b,384,64)  bf16

    float* y    = (float*)d_out;                   // (16,384,4096)
    float* hout = (float*)d_out + 25165824;        // (16,384,64)

    // 1) x -> xbT
    transpose_x<<<dim3(64, 6, 16), 256, 0, stream>>>(x, xbT);

    // 2) bcdt(bf16) = w_bcdt @ x[b]   (M=192, N=4096, K=384), 64x256 tiles
    gemm_bf16<256, 4, true, false, 2><<<dim3(16, 3, BATCH), 256, 0, stream>>>(
        w_bcdt, xbT, bcdt, C3, LTOK, DMODEL,
        0L, (long)LTOK * DMODEL, (long)C3 * LTOK, 16, 1);

    // 3) fused conv(Bm,dt) + softmax -> AB bf16
    conv_softmax_ab<<<dim3(BATCH * SDIM), 256, 0, stream>>>(bcdt, w_dw, AB);

    // 4) conv for Cm channels -> convCm f32
    dwconv_cm<<<dim3(BATCH * SDIM), 256, 0, stream>>>(bcdt, w_dw, convCm);

    // 5) convCm -> CmT bf16
    transpose_cm<<<dim3(64, 16), 256, 0, stream>>>(convCm, CmT);

    // 6) hT[b] (64x384) = AB[b] @ x[b]^T ; split-K=8 with atomics
    hipMemsetAsync(hT, 0, (size_t)BATCH * SDIM * DMODEL * 4, stream);
    gemm_bf16<128, 2, false, true, 1><<<dim3(3 * 8, 1, BATCH), 256, 0, stream>>>(
        AB, x, hT, SDIM, DMODEL, LTOK,
        (long)SDIM * LTOK, (long)DMODEL * LTOK, (long)SDIM * DMODEL, 3, 8);

    // 7) hzT[b] (64x1536) = hT[b] @ w_hz^T
    gemm_bf16<128, 2, true, true, 0><<<dim3(12, 1, BATCH), 256, 0, stream>>>(
        hT, w_hz, hzT, SDIM, 2 * DINNER, DMODEL,
        (long)SDIM * DMODEL, 0L, (long)SDIM * 2 * DINNER, 12, 1);

    // 8) gate
    gate_k<<<dim3((BATCH * SDIM * DINNER) / 256), 256, 0, stream>>>(hzT, dparam, gT);

    // 9) houtT[b] (64x384) = gT[b] @ w_out^T
    gemm_bf16<128, 2, true, true, 0><<<dim3(3, 1, BATCH), 256, 0, stream>>>(
        gT, w_out, houtT, SDIM, DMODEL, DINNER,
        (long)SDIM * DINNER, 0L, (long)SDIM * DMODEL, 3, 1);

    // 10) houtT -> hout + hb
    transpose_hout<<<dim3(6, 16), 256, 0, stream>>>(houtT, hout, hb);

    // 11) y[b] (384x4096) = hb[b] @ CmT[b]^T (K=64), 64x256 tiles
    gemm_bf16<256, 4, false, false, 0><<<dim3(16, 6, BATCH), 256, 0, stream>>>(
        hb, CmT, y, DMODEL, LTOK, SDIM,
        (long)DMODEL * SDIM, (long)LTOK * SDIM, (long)DMODEL * LTOK, 16, 1);
}

// Round 6
// 352.297 us; speedup vs baseline: 1.8886x; 1.0020x over previous
//
#include <hip/hip_runtime.h>
#include <hip/hip_bf16.h>

#define BATCH 16
#define DMODEL 384
#define LTOK 4096          // H*W
#define SDIM 64
#define C3 192
#define DINNER 768

typedef __attribute__((ext_vector_type(8))) short short8;
typedef __attribute__((ext_vector_type(4))) short short4v;
typedef __attribute__((ext_vector_type(4))) float f32x4;

__device__ __forceinline__ short f2bf(float f) {
    unsigned u = __builtin_bit_cast(unsigned, f);
    u += 0x7fffu + ((u >> 16) & 1u);   // round-to-nearest-even
    return (short)(u >> 16);
}
__device__ __forceinline__ float bf2f(short s) {
    return __builtin_bit_cast(float, ((unsigned)(unsigned short)s) << 16);
}

// ---------------------------------------------------------------------------
// Unified MFMA bf16 GEMM:  C(M x N) = A(M x K) * B(K x N)
// A: (M,K) row-major, row stride lda, batch stride sA.
//   AMODE 0: bf16.  1: fp32->bf16 on stage.  2: GATE: fp32 hz rows, stage
//            A[m][k] = hz[m][k] * (silu(hz[m][DINNER+k]) + d).
// B: stored TRANSPOSED (N,K) row-major, row stride ldb, batch stride sB.
//   BMODE 0: bf16.  1: fp32->bf16 on stage.
// CMODE 0: fp32 store C[row*N+col]
//       3: split-K partial fp32 store at ((kchunk*BATCH+b)*sC + row*N+col)
//       4: dual store (gate'd chain tail): hout fp32 (b,384,64) + hb bf16,
//          row encodes b*64+s, col = d.  (Cp=hout, Cp2=hb)
//       5: bf16 transposed store C^T -> Cp[col*M + row] (short4)
//       6: fp32 transposed store C^T -> Cp[col*M + row] (float4)
// Geometry: BM=64, BK=32, 4 waves; wave w owns cols [w*BN/4,(w+1)*BN/4).
// ---------------------------------------------------------------------------
template<int BN, int NF, int AMODE, int BMODE, int CMODE>
__global__ __launch_bounds__(256) void gemm_k(
    const void* __restrict__ Ap, const void* __restrict__ Bp,
    void* __restrict__ Cp, void* __restrict__ Cp2, const float* __restrict__ gp,
    int M, int N, int K, int lda, int ldb,
    long sA, long sB, long sC, int nTilesN, int splitK)
{
    const int b = blockIdx.z;
    const int ntile  = blockIdx.x % nTilesN;
    const int kchunk = blockIdx.x / nTilesN;
    const int row0 = blockIdx.y << 6;
    const int col0 = ntile * BN;
    const int kPer = K / splitK;
    const int kBeg = kchunk * kPer, kEnd = kBeg + kPer;

    __shared__ short As[64][40];
    __shared__ short Bs[BN][40];

    const int t = threadIdx.x;
    const int wid = t >> 6, lane = t & 63;
    const int lr = lane & 15;
    const int lk = (lane >> 4) << 3;
    const float dp = (AMODE == 2) ? gp[0] : 0.f;

    f32x4 acc[4][NF];
#pragma unroll
    for (int i = 0; i < 4; i++)
#pragma unroll
        for (int j = 0; j < NF; j++)
#pragma unroll
            for (int r = 0; r < 4; r++) acc[i][j][r] = 0.f;

    for (int kt = kBeg; kt < kEnd; kt += 32) {
        // ---- stage A tile (64 x 32) ----
        {
            const int arow = t >> 2, akb = (t & 3) << 3;
            if constexpr (AMODE == 0) {
                const short* s = (const short*)Ap + b * sA + (long)(row0 + arow) * lda + kt + akb;
                *(short8*)&As[arow][akb] = *(const short8*)s;
            } else if constexpr (AMODE == 1) {
                const float* s = (const float*)Ap + b * sA + (long)(row0 + arow) * lda + kt + akb;
                short8 v;
#pragma unroll
                for (int j = 0; j < 8; j++) v[j] = f2bf(s[j]);
                *(short8*)&As[arow][akb] = v;
            } else {  // AMODE 2: gate
                const float* s = (const float*)Ap + (long)(row0 + arow) * lda + kt + akb;
                short8 v;
#pragma unroll
                for (int j = 0; j < 8; j++) {
                    float hi = s[j], z = s[DINNER + j];
                    v[j] = f2bf(hi * (z / (1.f + __expf(-z)) + dp));
                }
                *(short8*)&As[arow][akb] = v;
            }
        }
        // ---- stage B tile (BN x 32) from (N,K)-transposed operand ----
#pragma unroll
        for (int rr = 0; rr < BN / 64; rr++) {
            const int u = t + rr * 256;
            const int brow = u >> 2, bkb = (u & 3) << 3;
            if constexpr (BMODE == 1) {
                const float* s = (const float*)Bp + b * sB + (long)(col0 + brow) * ldb + kt + bkb;
                short8 v;
#pragma unroll
                for (int j = 0; j < 8; j++) v[j] = f2bf(s[j]);
                *(short8*)&Bs[brow][bkb] = v;
            } else {
                const short* s = (const short*)Bp + b * sB + (long)(col0 + brow) * ldb + kt + bkb;
                *(short8*)&Bs[brow][bkb] = *(const short8*)s;
            }
        }
        __syncthreads();

        short8 af[4], bfr[NF];
#pragma unroll
        for (int mi = 0; mi < 4; mi++) af[mi] = *(const short8*)&As[mi * 16 + lr][lk];
#pragma unroll
        for (int ni = 0; ni < NF; ni++) bfr[ni] = *(const short8*)&Bs[wid * (BN / 4) + ni * 16 + lr][lk];
#pragma unroll
        for (int mi = 0; mi < 4; mi++)
#pragma unroll
            for (int ni = 0; ni < NF; ni++)
                acc[mi][ni] = __builtin_amdgcn_mfma_f32_16x16x32_bf16(af[mi], bfr[ni], acc[mi][ni], 0, 0, 0);
        __syncthreads();
    }

    const int hi4 = (lane >> 4) << 2;
#pragma unroll
    for (int mi = 0; mi < 4; mi++)
#pragma unroll
        for (int ni = 0; ni < NF; ni++) {
            const long row = row0 + mi * 16 + hi4;                 // first of 4 consecutive rows
            const long col = col0 + wid * (BN / 4) + ni * 16 + lr;
            if constexpr (CMODE == 0) {
#pragma unroll
                for (int r = 0; r < 4; r++)
                    ((float*)Cp)[b * sC + (row + r) * N + col] = acc[mi][ni][r];
            } else if constexpr (CMODE == 3) {
#pragma unroll
                for (int r = 0; r < 4; r++)
                    ((float*)Cp)[((long)kchunk * BATCH + b) * sC + (row + r) * N + col] = acc[mi][ni][r];
            } else if constexpr (CMODE == 4) {
                const long bb = row >> 6, s0 = row & 63;           // constant over r
                f32x4 fv = acc[mi][ni];
                *(f32x4*)((float*)Cp + ((bb * DMODEL) + col) * SDIM + s0) = fv;
                short4v sv;
#pragma unroll
                for (int r = 0; r < 4; r++) sv[r] = f2bf(acc[mi][ni][r]);
                *(short4v*)((short*)Cp2 + ((bb * DMODEL) + col) * SDIM + s0) = sv;
            } else if constexpr (CMODE == 5) {
                short4v sv;
#pragma unroll
                for (int r = 0; r < 4; r++) sv[r] = f2bf(acc[mi][ni][r]);
                *(short4v*)((short*)Cp + b * sC + col * (long)M + row) = sv;
            } else {  // 6
                *(f32x4*)((float*)Cp + b * sC + col * (long)M + row) = acc[mi][ni];
            }
        }
}

// x (b,384,4096 f32) -> xbT (b,4096,384 bf16), 64x64 LDS tiles
__global__ __launch_bounds__(256) void transpose_x(const float* __restrict__ x, short* __restrict__ xbT)
{
    const int b = blockIdx.z;
    const int l0 = blockIdx.x << 6, d0 = blockIdx.y << 6;
    __shared__ float tl[64][65];
    const int t = threadIdx.x, c = t & 63, r0 = t >> 6;
    const float* ip = x + ((long)b * DMODEL + d0) * LTOK + l0;
    for (int d = r0; d < 64; d += 4) tl[d][c] = ip[(long)d * LTOK + c];
    __syncthreads();
    short* op = xbT + ((long)b * LTOK + l0) * DMODEL + d0;
    for (int l = r0; l < 64; l += 4) op[(long)l * DMODEL + c] = f2bf(tl[c][l]);
}

// Fused: depthwise 3x3 conv of Bm(ch s) and dt(ch 128+s) + softmax(dt)*Bm -> AB bf16
__global__ __launch_bounds__(256) void conv_softmax_ab(
    const short* __restrict__ bcdt, const float* __restrict__ w_dw, short* __restrict__ AB)
{
    const int b = blockIdx.x >> 6, s = blockIdx.x & 63;
    __shared__ float pB[4096];
    __shared__ float pD[4096];
    __shared__ float wB[9], wD[9];
    __shared__ float redm[4], reds[4];
    const int t = threadIdx.x;

    const short* srcB = bcdt + ((long)b * C3 + s) * 4096;
    const short* srcD = bcdt + ((long)b * C3 + 128 + s) * 4096;
#pragma unroll
    for (int j = 0; j < 2; j++) {
        const int o = (t + j * 256) * 8;
        short8 vb = *(const short8*)(srcB + o);
        short8 vd = *(const short8*)(srcD + o);
#pragma unroll
        for (int e = 0; e < 8; e++) { pB[o + e] = bf2f(vb[e]); pD[o + e] = bf2f(vd[e]); }
    }
    if (t < 9) { wB[t] = w_dw[s * 9 + t]; wD[t] = w_dw[(128 + s) * 9 + t]; }
    __syncthreads();

    float v[16];
    float mx = -1e30f;
#pragma unroll
    for (int i = 0; i < 16; i++) {
        const int l = t + i * 256, y = l >> 6, x = l & 63;
        float sacc = 0.f;
#pragma unroll
        for (int dy = -1; dy <= 1; dy++)
#pragma unroll
            for (int dx = -1; dx <= 1; dx++) {
                int yy = y + dy, xx = x + dx;
                if (yy >= 0 && yy < 64 && xx >= 0 && xx < 64)
                    sacc += pD[yy * 64 + xx] * wD[(dy + 1) * 3 + (dx + 1)];
            }
        v[i] = sacc; mx = fmaxf(mx, sacc);
    }
#pragma unroll
    for (int o = 32; o > 0; o >>= 1) mx = fmaxf(mx, __shfl_xor(mx, o));
    const int wid = t >> 6;
    if ((t & 63) == 0) redm[wid] = mx;
    __syncthreads();
    mx = fmaxf(fmaxf(redm[0], redm[1]), fmaxf(redm[2], redm[3]));

    float sum = 0.f;
#pragma unroll
    for (int i = 0; i < 16; i++) { v[i] = __expf(v[i] - mx); sum += v[i]; }
#pragma unroll
    for (int o = 32; o > 0; o >>= 1) sum += __shfl_xor(sum, o);
    if ((t & 63) == 0) reds[wid] = sum;
    __syncthreads();
    sum = reds[0] + reds[1] + reds[2] + reds[3];
    const float inv = 1.0f / sum;

    short* ab = AB + ((long)b * SDIM + s) * (long)LTOK;
#pragma unroll
    for (int i = 0; i < 16; i++) {
        const int l = t + i * 256, y = l >> 6, x = l & 63;
        float uacc = 0.f;
#pragma unroll
        for (int dy = -1; dy <= 1; dy++)
#pragma unroll
            for (int dx = -1; dx <= 1; dx++) {
                int yy = y + dy, xx = x + dx;
                if (yy >= 0 && yy < 64 && xx >= 0 && xx < 64)
                    uacc += pB[yy * 64 + xx] * wB[(dy + 1) * 3 + (dx + 1)];
            }
        ab[l] = f2bf(v[i] * inv * uacc);
    }
}

// Depthwise conv for Cm channels (c = 64+cc), bf16 in, fp32 out (b,64,4096)
__global__ __launch_bounds__(256) void dwconv_cm(
    const short* __restrict__ bcdt, const float* __restrict__ w, float* __restrict__ convCm)
{
    const int bc = blockIdx.x;
    const int b = bc >> 6, cc = bc & 63;
    __shared__ float tile[4096];
    __shared__ float wc[9];
    const short* ip = bcdt + ((long)b * C3 + 64 + cc) * 4096;
    const int t = threadIdx.x;
#pragma unroll
    for (int j = 0; j < 2; j++) {
        const int o = (t + j * 256) * 8;
        short8 vv = *(const short8*)(ip + o);
#pragma unroll
        for (int e = 0; e < 8; e++) tile[o + e] = bf2f(vv[e]);
    }
    if (t < 9) wc[t] = w[(64 + cc) * 9 + t];
    __syncthreads();
    float* op = convCm + (long)bc * 4096;
    for (int i = t; i < 4096; i += 256) {
        int y = i >> 6, x = i & 63;
        float sacc = 0.f;
#pragma unroll
        for (int dy = -1; dy <= 1; dy++)
#pragma unroll
            for (int dx = -1; dx <= 1; dx++) {
                int yy = y + dy, xx = x + dx;
                if (yy >= 0 && yy < 64 && xx >= 0 && xx < 64)
                    sacc += tile[yy * 64 + xx] * wc[(dy + 1) * 3 + (dx + 1)];
            }
        op[i] = sacc;
    }
}

// convCm (b,64,4096 f32) -> CmT (b,4096,64 bf16)
__global__ __launch_bounds__(256) void transpose_cm(
    const float* __restrict__ convCm, short* __restrict__ CmT)
{
    const int b = blockIdx.y, l0 = blockIdx.x << 6;
    __shared__ float tl[64][65];
    const int t = threadIdx.x, c = t & 63, r0 = t >> 6;
    const float* ip = convCm + (long)b * SDIM * LTOK + l0;
    for (int s = r0; s < 64; s += 4) tl[s][c] = ip[(long)s * LTOK + c];
    __syncthreads();
    short* op = CmT + ((long)b * LTOK + l0) * SDIM;
    for (int l = r0; l < 64; l += 4) op[(long)l * SDIM + c] = f2bf(tl[c][l]);
}

// part (8, 1024, 384) f32  ->  hT bf16 stacked (1024, 384)
__global__ __launch_bounds__(256) void reduce8(
    const float* __restrict__ part, short* __restrict__ hT)
{
    const long i4 = (long)blockIdx.x * 256 + threadIdx.x;   // float4 index, 98304 total
    const long base = i4 * 4;
    f32x4 sum = *(const f32x4*)(part + base);
#pragma unroll
    for (int c = 1; c < 8; c++) {
        f32x4 v = *(const f32x4*)(part + (long)c * 393216 + base);
#pragma unroll
        for (int r = 0; r < 4; r++) sum[r] += v[r];
    }
    short4v sv;
#pragma unroll
    for (int r = 0; r < 4; r++) sv[r] = f2bf(sum[r]);
    *(short4v*)(hT + base) = sv;
}

extern "C" void kernel_launch(void* const* d_in, const int* in_sizes, int n_in,
                              void* d_out, int out_size, void* d_ws, size_t ws_size,
                              hipStream_t stream) {
    const float* x      = (const float*)d_in[0];   // (16,384,4096)
    const float* w_bcdt = (const float*)d_in[1];   // (192,384)
    const float* w_dw   = (const float*)d_in[2];   // (192,1,3,3)
    const float* w_hz   = (const float*)d_in[3];   // (1536,384)
    const float* w_out  = (const float*)d_in[4];   // (384,768)
    const float* dparam = (const float*)d_in[6];   // (1,)

    char* ws = (char*)d_ws;
    short* xbT    = (short*)(ws);                  // 50.33 MB (b,4096,384) bf16  [dead after gemm1]
    float* part   = (float*)(ws);                  // 12.58 MB (8,1024,384) f32   [reuses xbT region]
    short* hT     = (short*)(ws + 12582912);       //  0.79 MB (1024,384) bf16
    float* hzT    = (float*)(ws + 13631488);       //  6.29 MB (1024,1536) f32
    short* hb     = (short*)(ws + 19922944);       //  0.79 MB (b,384,64) bf16
    short* bcdt   = (short*)(ws + 50331648);       // 25.17 MB (b,192,4096) bf16
    short* AB     = (short*)(ws + 75497472);       //  8.39 MB (b,64,4096)  bf16
    float* convCm = (float*)(ws + 83886080);       // 16.78 MB (b,64,4096)  f32
    short* CmT    = (short*)(ws + 100663296);      //  8.39 MB (b,4096,64)  bf16

    float* y    = (float*)d_out;                   // (16,384,4096)
    float* hout = (float*)d_out + 25165824;        // (16,384,64)

    // 1) x -> xbT
    transpose_x<<<dim3(64, 6, 16), 256, 0, stream>>>(x, xbT);

    // 2) bcdt^T: C'(4096x192) = xbT(4096x384) @ w_bcdt^T, bf16 transposed store
    gemm_k<192, 3, 0, 1, 5><<<dim3(1, 64, 16), 256, 0, stream>>>(
        xbT, w_bcdt, bcdt, nullptr, nullptr,
        LTOK, C3, DMODEL, DMODEL, DMODEL,
        (long)LTOK * DMODEL, 0L, (long)C3 * LTOK, 1, 1);

    // 3) fused conv(Bm,dt)+softmax -> AB bf16
    conv_softmax_ab<<<dim3(BATCH * SDIM), 256, 0, stream>>>(bcdt, w_dw, AB);

    // 4) conv Cm -> convCm f32
    dwconv_cm<<<dim3(BATCH * SDIM), 256, 0, stream>>>(bcdt, w_dw, convCm);

    // 5) convCm -> CmT bf16
    transpose_cm<<<dim3(64, 16), 256, 0, stream>>>(convCm, CmT);

    // 6) part[kc,b] (64x384) = AB[b] @ x[b]^T  (K=4096, split-K=8, no atomics)
    gemm_k<128, 2, 0, 1, 3><<<dim3(3 * 8, 1, 16), 256, 0, stream>>>(
        AB, x, part, nullptr, nullptr,
        SDIM, DMODEL, LTOK, LTOK, LTOK,
        (long)SDIM * LTOK, (long)DMODEL * LTOK, (long)SDIM * DMODEL, 3, 8);

    // 7) reduce partials -> hT bf16 stacked (1024,384)
    reduce8<<<dim3(384), 256, 0, stream>>>(part, hT);

    // 8) hzT (1024x1536) = hT @ w_hz^T  (stacked, K=384)
    gemm_k<128, 2, 0, 1, 0><<<dim3(12, 16, 1), 256, 0, stream>>>(
        hT, w_hz, hzT, nullptr, nullptr,
        1024, 2 * DINNER, DMODEL, DMODEL, DMODEL,
        0L, 0L, 0L, 12, 1);

    // 9) hout+hb = gate(hzT) @ w_out^T  (stacked, K=768, gate in A-staging,
    //    dual transposed epilogue -> hout fp32 (b,384,64) + hb bf16)
    gemm_k<64, 1, 2, 1, 4><<<dim3(6, 16, 1), 256, 0, stream>>>(
        hzT, w_out, hout, hb, dparam,
        1024, DMODEL, DINNER, 2 * DINNER, DINNER,
        0L, 0L, 0L, 6, 1);

    // 10) y^T: C'(4096x384) = CmT(4096x64) @ hb^T  (K=64), fp32 transposed store
    gemm_k<128, 2, 0, 0, 6><<<dim3(3, 64, 16), 256, 0, stream>>>(
        CmT, hb, y, nullptr, nullptr,
        LTOK, DMODEL, SDIM, SDIM, SDIM,
        (long)LTOK * SDIM, (long)DMODEL * SDIM, (long)DMODEL * LTOK, 3, 1);
}